// Round 2
// baseline (3134.309 us; speedup 1.0000x reference)
//
#include <hip/hip_runtime.h>
#include <hip/hip_bf16.h>

typedef __bf16 bf16;
typedef __attribute__((ext_vector_type(8))) __bf16 bf16x8;
typedef __attribute__((ext_vector_type(4))) float f32x4;

#define TOKENS 15360   // B*S = 16*960
#define HID    512
#define FFN_D  2048
#define QKV_D  1536

// ---------------------------------------------------------------------------
// fp32 -> bf16 weight conversion (run every launch; ws is re-poisoned)
// ---------------------------------------------------------------------------
__global__ __launch_bounds__(256) void cvt_kernel(const float* __restrict__ src,
                                                  bf16* __restrict__ dst, int n4) {
  const int i = (blockIdx.x * 256 + threadIdx.x);
  if (i >= n4) return;
  const float4 v = ((const float4*)src)[i];
  bf16* d = dst + (size_t)i * 4;
  d[0] = (bf16)v.x; d[1] = (bf16)v.y; d[2] = (bf16)v.z; d[3] = (bf16)v.w;
}

// ---------------------------------------------------------------------------
// GEMM: C[M,N] = A[M,K] @ W[N,K]^T (+bias fp32, + optional residual / GELU)
// 128x128 tile, BK=64, 4 waves, each 64x64 via 4x4 mfma_f32_16x16x32_bf16.
// LDS staged with global_load_lds width=16; XOR swizzle (slot c holds k-chunk
// c^(r&7)) keeps async-copy contiguity AND makes ds_read_b128 2-way (free).
// ---------------------------------------------------------------------------
#define EPI_BIAS_BF16     0
#define EPI_BIAS_RES_F32  1
#define EPI_BIAS_GELU     2

template <int EPI>
__global__ __launch_bounds__(256) void gemm_bt(
    const bf16* __restrict__ A, const bf16* __restrict__ W,
    const float* __restrict__ bias, const bf16* __restrict__ R,
    void* __restrict__ out, int M, int N, int K) {
  __shared__ __align__(16) bf16 As[128 * 64];
  __shared__ __align__(16) bf16 Bs[128 * 64];

  const int tid  = threadIdx.x;
  const int lane = tid & 63;
  const int wv   = tid >> 6;
  const int li   = lane & 15;
  const int qd   = lane >> 4;
  const int mw   = (wv & 1) << 6;
  const int nw   = (wv >> 1) << 6;
  const int m0   = blockIdx.x << 7;
  const int n0   = blockIdx.y << 7;

  f32x4 acc[4][4];
#pragma unroll
  for (int i = 0; i < 4; ++i)
#pragma unroll
    for (int j = 0; j < 4; ++j) acc[i][j] = (f32x4){0.f, 0.f, 0.f, 0.f};

  const bf16* Abase = A + (size_t)m0 * K;
  const bf16* Wbase = W + (size_t)n0 * K;

  for (int k0 = 0; k0 < K; k0 += 64) {
#pragma unroll
    for (int it = 0; it < 4; ++it) {
      const int fc   = it * 256 + tid;       // chunk id: row r, slot c
      const int r    = fc >> 3;
      const int c    = fc & 7;
      const int koff = (c ^ (r & 7)) << 3;   // swizzled k-chunk
      const bf16* asrc = Abase + (size_t)r * K + k0 + koff;
      const bf16* bsrc = Wbase + (size_t)r * K + k0 + koff;
      bf16* adst = As + (size_t)(it * 256 + (tid & 192)) * 8;  // wave-uniform
      bf16* bdst = Bs + (size_t)(it * 256 + (tid & 192)) * 8;
      __builtin_amdgcn_global_load_lds(
          (const __attribute__((address_space(1))) unsigned int*)asrc,
          (__attribute__((address_space(3))) unsigned int*)adst, 16, 0, 0);
      __builtin_amdgcn_global_load_lds(
          (const __attribute__((address_space(1))) unsigned int*)bsrc,
          (__attribute__((address_space(3))) unsigned int*)bdst, 16, 0, 0);
    }
    __syncthreads();

#pragma unroll
    for (int ks = 0; ks < 2; ++ks) {
      const int ck = (ks << 2) + qd;         // A/B frag: k-chunk = quad (+4*ks)
      bf16x8 af[4], bfv[4];
#pragma unroll
      for (int i = 0; i < 4; ++i) {
        const int mr = mw + i * 16 + li;     // mr&7 == li&7
        af[i] = *(const bf16x8*)(As + mr * 64 + ((ck ^ (li & 7)) << 3));
      }
#pragma unroll
      for (int j = 0; j < 4; ++j) {
        const int nr = nw + j * 16 + li;
        bfv[j] = *(const bf16x8*)(Bs + nr * 64 + ((ck ^ (li & 7)) << 3));
      }
#pragma unroll
      for (int i = 0; i < 4; ++i)
#pragma unroll
        for (int j = 0; j < 4; ++j)
          acc[i][j] = __builtin_amdgcn_mfma_f32_16x16x32_bf16(af[i], bfv[j],
                                                              acc[i][j], 0, 0, 0);
    }
    __syncthreads();
  }

  // epilogue: C/D layout col=lane&15, row=(lane>>4)*4+reg  [m89/m91 verified]
#pragma unroll
  for (int i = 0; i < 4; ++i) {
    const int mrow = m0 + mw + i * 16 + qd * 4;
#pragma unroll
    for (int j = 0; j < 4; ++j) {
      const int ncol = n0 + nw + j * 16 + li;
      const float bv = bias[ncol];
#pragma unroll
      for (int r = 0; r < 4; ++r) {
        const size_t off = (size_t)(mrow + r) * N + ncol;
        float v = acc[i][j][r] + bv;
        if (EPI == EPI_BIAS_RES_F32) {
          ((float*)out)[off] = v + (float)R[off];
        } else if (EPI == EPI_BIAS_GELU) {
          v = 0.5f * v * (1.f + erff(v * 0.70710678118654752f));
          ((bf16*)out)[off] = (bf16)v;
        } else {
          ((bf16*)out)[off] = (bf16)v;
        }
      }
    }
  }
}

// ---------------------------------------------------------------------------
// Attention: one block per (sequence, head). qkv row = [q(512)|k(512)|v(512)].
// fp32 LDS (+pad -> conflict-free), fp32 softmax, bf16 out.
// ---------------------------------------------------------------------------
template <int P>
__global__ __launch_bounds__(256) void attn_kernel(const bf16* __restrict__ qkv,
                                                   bf16* __restrict__ out) {
  __shared__ float Qs[P][65];
  __shared__ float Ks[P][65];
  __shared__ float Vs[P][65];
  __shared__ float Ss[P][P + 1];

  const int tid = threadIdx.x;
  const int n   = blockIdx.x >> 3;
  const int h   = blockIdx.x & 7;
  const bf16* base = qkv + (size_t)n * P * QKV_D + h * 64;

  for (int e = tid; e < P * 64; e += 256) {
    const int r = e >> 6, d = e & 63;
    const bf16* p = base + (size_t)r * QKV_D + d;
    Qs[r][d] = (float)p[0];
    Ks[r][d] = (float)p[512];
    Vs[r][d] = (float)p[1024];
  }
  __syncthreads();

  constexpr int TT = (P >= 48) ? 4 : 2;
  constexpr int NT = P / TT;
  for (int t = tid; t < NT * NT; t += 256) {
    const int ti = t / NT;
    const int tj = t % NT;
    float a[TT][TT];
#pragma unroll
    for (int ii = 0; ii < TT; ++ii)
#pragma unroll
      for (int jj = 0; jj < TT; ++jj) a[ii][jj] = 0.f;
#pragma unroll 4
    for (int d = 0; d < 64; ++d) {
      float qv[TT], kv[TT];
#pragma unroll
      for (int ii = 0; ii < TT; ++ii) qv[ii] = Qs[ti + ii * NT][d];
#pragma unroll
      for (int jj = 0; jj < TT; ++jj) kv[jj] = Ks[tj + jj * NT][d];
#pragma unroll
      for (int ii = 0; ii < TT; ++ii)
#pragma unroll
        for (int jj = 0; jj < TT; ++jj) a[ii][jj] += qv[ii] * kv[jj];
    }
#pragma unroll
    for (int ii = 0; ii < TT; ++ii)
#pragma unroll
      for (int jj = 0; jj < TT; ++jj)
        Ss[ti + ii * NT][tj + jj * NT] = a[ii][jj] * 0.125f;  // 1/sqrt(64)
  }
  __syncthreads();

  if (tid < P) {
    const int i = tid;
    float mx = -1e30f;
    for (int j = 0; j < P; ++j) mx = fmaxf(mx, Ss[i][j]);
    float sum = 0.f;
    for (int j = 0; j < P; ++j) {
      const float ev = __expf(Ss[i][j] - mx);
      Ss[i][j] = ev;
      sum += ev;
    }
    const float inv = 1.f / sum;
    for (int j = 0; j < P; ++j) Ss[i][j] *= inv;
  }
  __syncthreads();

  constexpr int NTI = P / 4;
  for (int t = tid; t < NTI * 16; t += 256) {
    const int ti = t >> 4;
    const int td = t & 15;
    float a[4][4];
#pragma unroll
    for (int ii = 0; ii < 4; ++ii)
#pragma unroll
      for (int dd = 0; dd < 4; ++dd) a[ii][dd] = 0.f;
    for (int j = 0; j < P; ++j) {
      float sv[4], vv[4];
#pragma unroll
      for (int ii = 0; ii < 4; ++ii) sv[ii] = Ss[ti + ii * NTI][j];
#pragma unroll
      for (int dd = 0; dd < 4; ++dd) vv[dd] = Vs[j][td + dd * 16];
#pragma unroll
      for (int ii = 0; ii < 4; ++ii)
#pragma unroll
        for (int dd = 0; dd < 4; ++dd) a[ii][dd] += sv[ii] * vv[dd];
    }
#pragma unroll
    for (int ii = 0; ii < 4; ++ii) {
      const size_t ro = (size_t)(n * P + ti + ii * NTI) * HID + h * 64 + td;
#pragma unroll
      for (int dd = 0; dd < 4; ++dd) out[ro + dd * 16] = (bf16)a[ii][dd];
    }
  }
}

// ---------------------------------------------------------------------------
// LayerNorm over 512, one wave per row. Y fp32 in, params fp32, bf16 out.
// ---------------------------------------------------------------------------
__global__ __launch_bounds__(256) void ln_kernel(const float* __restrict__ Y,
                                                 const float* __restrict__ w,
                                                 const float* __restrict__ b,
                                                 bf16* __restrict__ X) {
  const int row  = blockIdx.x * 4 + (threadIdx.x >> 6);
  const int lane = threadIdx.x & 63;
  const float* y = Y + (size_t)row * HID;
  float v[8], s = 0.f, s2 = 0.f;
#pragma unroll
  for (int j = 0; j < 8; ++j) {
    v[j] = y[lane + 64 * j];
    s += v[j];
    s2 += v[j] * v[j];
  }
#pragma unroll
  for (int off = 32; off > 0; off >>= 1) {
    s  += __shfl_xor(s, off, 64);
    s2 += __shfl_xor(s2, off, 64);
  }
  const float mean = s * (1.f / 512.f);
  const float var  = s2 * (1.f / 512.f) - mean * mean;
  const float rstd = rsqrtf(var + 1e-5f);
  bf16* xr = X + (size_t)row * HID;
#pragma unroll
  for (int j = 0; j < 8; ++j) {
    const int c = lane + 64 * j;
    xr[c] = (bf16)((v[j] - mean) * rstd * w[c] + b[c]);
  }
}

// ---------------------------------------------------------------------------
// input projection: h[r,o] = sum_k x[r,k]*w[o,k] + b[o], K=7 (fp32 in, bf16 out)
// ---------------------------------------------------------------------------
__global__ __launch_bounds__(256) void inproj_kernel(const float* __restrict__ x,
                                                     const float* __restrict__ w,
                                                     const float* __restrict__ b,
                                                     bf16* __restrict__ h) {
  const int idx = blockIdx.x * 256 + threadIdx.x;
  const int r = idx >> 9, o = idx & 511;
  float s = b[o];
#pragma unroll
  for (int k = 0; k < 7; ++k) s += x[r * 7 + k] * w[o * 7 + k];
  h[idx] = (bf16)s;
}

// acc[row] (+)= X[row,:] . w  (per-branch final projection accumulate)
__global__ __launch_bounds__(256) void outdot_kernel(const bf16* __restrict__ X,
                                                     const float* __restrict__ w,
                                                     float* __restrict__ acc,
                                                     int first) {
  const int row  = blockIdx.x * 4 + (threadIdx.x >> 6);
  const int lane = threadIdx.x & 63;
  const bf16* xr = X + (size_t)row * HID;
  float s = 0.f;
#pragma unroll
  for (int j = 0; j < 8; ++j) {
    const int c = lane + 64 * j;
    s += (float)xr[c] * w[c];
  }
#pragma unroll
  for (int off = 32; off > 0; off >>= 1) s += __shfl_xor(s, off, 64);
  if (lane == 0) acc[row] = first ? s : (acc[row] + s);
}

// out[b,o] = (1/30) * sum_{j<10} acc[b*960 + o*10 + j] + b_out   (fp32 out)
__global__ __launch_bounds__(256) void pool_kernel(const float* __restrict__ acc,
                                                   const float* __restrict__ ob,
                                                   float* __restrict__ out) {
  const int idx = blockIdx.x * 256 + threadIdx.x;
  if (idx >= 16 * 96) return;
  const int bb = idx / 96, o = idx % 96;
  float s = 0.f;
#pragma unroll
  for (int j = 0; j < 10; ++j) s += acc[bb * 960 + o * 10 + j];
  out[idx] = s * (1.f / 30.f) + ob[0];
}

// ---------------------------------------------------------------------------
extern "C" void kernel_launch(void* const* d_in, const int* in_sizes, int n_in,
                              void* d_out, int out_size, void* d_ws,
                              size_t ws_size, hipStream_t stream) {
  const float* x          = (const float*)d_in[0];
  const float* ip_w       = (const float*)d_in[1];
  const float* ip_b       = (const float*)d_in[2];
  const float* in_proj_w  = (const float*)d_in[3];
  const float* in_proj_b  = (const float*)d_in[4];
  const float* out_proj_w = (const float*)d_in[5];
  const float* out_proj_b = (const float*)d_in[6];
  const float* ffn_w1     = (const float*)d_in[7];
  const float* ffn_b1     = (const float*)d_in[8];
  const float* ffn_w2     = (const float*)d_in[9];
  const float* ffn_b2     = (const float*)d_in[10];
  const float* ln1_w      = (const float*)d_in[11];
  const float* ln1_b      = (const float*)d_in[12];
  const float* ln2_w      = (const float*)d_in[13];
  const float* ln2_b      = (const float*)d_in[14];
  const float* op_w       = (const float*)d_in[15];
  const float* op_b       = (const float*)d_in[16];

  // workspace layout (~135.4 MB; R0 proved ws_size >= 142 MB)
  char* ws = (char*)d_ws;
  float* Y   = (float*)ws; ws += (size_t)TOKENS * HID * 4;     // 31.5 MB
  bf16* Xb   = (bf16*)ws;  ws += (size_t)TOKENS * HID * 2;     // 15.7 MB
  bf16* SCR  = (bf16*)ws;  ws += (size_t)TOKENS * FFN_D * 2;   // 62.9 MB
  bf16* ATT  = SCR + (size_t)TOKENS * QKV_D;                   // tail of SCR
  float* ACC = (float*)ws; ws += (size_t)TOKENS * 4;
  bf16* Wq   = (bf16*)ws;  ws += (size_t)4 * QKV_D * HID * 2;  // 6.3 MB
  bf16* Wo   = (bf16*)ws;  ws += (size_t)4 * HID * HID * 2;    // 2.1 MB
  bf16* W1   = (bf16*)ws;  ws += (size_t)4 * FFN_D * HID * 2;  // 8.4 MB
  bf16* W2   = (bf16*)ws;  ws += (size_t)4 * HID * FFN_D * 2;  // 8.4 MB
  if ((size_t)(ws - (char*)d_ws) > ws_size) return;

  // weight conversion fp32 -> bf16 (every call; ws is re-poisoned each call)
  {
    const int nq = 4 * QKV_D * HID / 4, no = 4 * HID * HID / 4,
              n1 = 4 * FFN_D * HID / 4, n2 = 4 * HID * FFN_D / 4;
    cvt_kernel<<<(nq + 255) / 256, 256, 0, stream>>>(in_proj_w, Wq, nq);
    cvt_kernel<<<(no + 255) / 256, 256, 0, stream>>>(out_proj_w, Wo, no);
    cvt_kernel<<<(n1 + 255) / 256, 256, 0, stream>>>(ffn_w1, W1, n1);
    cvt_kernel<<<(n2 + 255) / 256, 256, 0, stream>>>(ffn_w2, W2, n2);
  }

  const int MB = TOKENS / 128;  // 120 m-tiles

  static const int periods[3] = {24, 48, 96};
  for (int br = 0; br < 3; ++br) {
    const int P = periods[br];
    inproj_kernel<<<TOKENS * HID / 256, 256, 0, stream>>>(x, ip_w, ip_b, Xb);
    for (int l = 0; l < 4; ++l) {
      // QKV
      gemm_bt<EPI_BIAS_BF16><<<dim3(MB, QKV_D / 128), 256, 0, stream>>>(
          Xb, Wq + (size_t)l * QKV_D * HID, in_proj_b + l * QKV_D, nullptr,
          SCR, TOKENS, QKV_D, HID);
      // attention
      const int nblk = (TOKENS / P) * 8;
      if (P == 24)
        attn_kernel<24><<<nblk, 256, 0, stream>>>(SCR, ATT);
      else if (P == 48)
        attn_kernel<48><<<nblk, 256, 0, stream>>>(SCR, ATT);
      else
        attn_kernel<96><<<nblk, 256, 0, stream>>>(SCR, ATT);
      // out-proj + residual -> Y (fp32)
      gemm_bt<EPI_BIAS_RES_F32><<<dim3(MB, HID / 128), 256, 0, stream>>>(
          ATT, Wo + (size_t)l * HID * HID, out_proj_b + l * HID, Xb, Y,
          TOKENS, HID, HID);
      ln_kernel<<<TOKENS / 4, 256, 0, stream>>>(Y, ln1_w + l * HID,
                                                ln1_b + l * HID, Xb);
      // FFN1 + GELU
      gemm_bt<EPI_BIAS_GELU><<<dim3(MB, FFN_D / 128), 256, 0, stream>>>(
          Xb, W1 + (size_t)l * FFN_D * HID, ffn_b1 + l * FFN_D, nullptr,
          SCR, TOKENS, FFN_D, HID);
      // FFN2 + residual -> Y (fp32)
      gemm_bt<EPI_BIAS_RES_F32><<<dim3(MB, HID / 128), 256, 0, stream>>>(
          SCR, W2 + (size_t)l * HID * FFN_D, ffn_b2 + l * HID, Xb, Y,
          TOKENS, HID, FFN_D);
      ln_kernel<<<TOKENS / 4, 256, 0, stream>>>(Y, ln2_w + l * HID,
                                                ln2_b + l * HID, Xb);
    }
    outdot_kernel<<<TOKENS / 4, 256, 0, stream>>>(Xb, op_w, ACC, br == 0);
  }
  pool_kernel<<<6, 256, 0, stream>>>(ACC, op_b, (float*)d_out);
}

// Round 3
// 2467.031 us; speedup vs baseline: 1.2705x; 1.2705x over previous
//
#include <hip/hip_runtime.h>
#include <hip/hip_bf16.h>

typedef __bf16 bf16;
typedef __attribute__((ext_vector_type(8))) __bf16 bf16x8;
typedef __attribute__((ext_vector_type(4))) float f32x4;

#define TOKENS 15360   // B*S = 16*960
#define HID    512
#define FFN_D  2048
#define QKV_D  1536

// ---------------------------------------------------------------------------
// fp32 -> bf16 weight conversion (run every launch; ws is re-poisoned)
// ---------------------------------------------------------------------------
__global__ __launch_bounds__(256) void cvt_kernel(const float* __restrict__ src,
                                                  bf16* __restrict__ dst, int n4) {
  const int i = (blockIdx.x * 256 + threadIdx.x);
  if (i >= n4) return;
  const float4 v = ((const float4*)src)[i];
  bf16* d = dst + (size_t)i * 4;
  d[0] = (bf16)v.x; d[1] = (bf16)v.y; d[2] = (bf16)v.z; d[3] = (bf16)v.w;
}

// ---------------------------------------------------------------------------
// GEMM: C[M,N] = A[M,K] @ W[N,K]^T (+bias fp32, + optional residual / GELU)
// 128x128 tile, BK=64, 4 waves, each 64x64 via 4x4 mfma_f32_16x16x32_bf16.
// LDS staged with global_load_lds width=16; XOR swizzle (slot c holds k-chunk
// c^(r&7)) keeps async-copy contiguity AND makes ds_read_b128 2-way (free).
// ---------------------------------------------------------------------------
#define EPI_BIAS_BF16     0
#define EPI_BIAS_RES_F32  1
#define EPI_BIAS_GELU     2

template <int EPI>
__global__ __launch_bounds__(256) void gemm_bt(
    const bf16* __restrict__ A, const bf16* __restrict__ W,
    const float* __restrict__ bias, const bf16* __restrict__ R,
    void* __restrict__ out, int M, int N, int K) {
  __shared__ __align__(16) bf16 As[128 * 64];
  __shared__ __align__(16) bf16 Bs[128 * 64];

  const int tid  = threadIdx.x;
  const int lane = tid & 63;
  const int wv   = tid >> 6;
  const int li   = lane & 15;
  const int qd   = lane >> 4;
  const int mw   = (wv & 1) << 6;
  const int nw   = (wv >> 1) << 6;
  const int m0   = blockIdx.x << 7;
  const int n0   = blockIdx.y << 7;

  f32x4 acc[4][4];
#pragma unroll
  for (int i = 0; i < 4; ++i)
#pragma unroll
    for (int j = 0; j < 4; ++j) acc[i][j] = (f32x4){0.f, 0.f, 0.f, 0.f};

  const bf16* Abase = A + (size_t)m0 * K;
  const bf16* Wbase = W + (size_t)n0 * K;

  for (int k0 = 0; k0 < K; k0 += 64) {
#pragma unroll
    for (int it = 0; it < 4; ++it) {
      const int fc   = it * 256 + tid;       // chunk id: row r, slot c
      const int r    = fc >> 3;
      const int c    = fc & 7;
      const int koff = (c ^ (r & 7)) << 3;   // swizzled k-chunk
      const bf16* asrc = Abase + (size_t)r * K + k0 + koff;
      const bf16* bsrc = Wbase + (size_t)r * K + k0 + koff;
      bf16* adst = As + (size_t)(it * 256 + (tid & 192)) * 8;  // wave-uniform
      bf16* bdst = Bs + (size_t)(it * 256 + (tid & 192)) * 8;
      __builtin_amdgcn_global_load_lds(
          (const __attribute__((address_space(1))) unsigned int*)asrc,
          (__attribute__((address_space(3))) unsigned int*)adst, 16, 0, 0);
      __builtin_amdgcn_global_load_lds(
          (const __attribute__((address_space(1))) unsigned int*)bsrc,
          (__attribute__((address_space(3))) unsigned int*)bdst, 16, 0, 0);
    }
    __syncthreads();

#pragma unroll
    for (int ks = 0; ks < 2; ++ks) {
      const int ck = (ks << 2) + qd;         // A/B frag: k-chunk = quad (+4*ks)
      bf16x8 af[4], bfv[4];
#pragma unroll
      for (int i = 0; i < 4; ++i) {
        const int mr = mw + i * 16 + li;     // mr&7 == li&7
        af[i] = *(const bf16x8*)(As + mr * 64 + ((ck ^ (li & 7)) << 3));
      }
#pragma unroll
      for (int j = 0; j < 4; ++j) {
        const int nr = nw + j * 16 + li;
        bfv[j] = *(const bf16x8*)(Bs + nr * 64 + ((ck ^ (li & 7)) << 3));
      }
#pragma unroll
      for (int i = 0; i < 4; ++i)
#pragma unroll
        for (int j = 0; j < 4; ++j)
          acc[i][j] = __builtin_amdgcn_mfma_f32_16x16x32_bf16(af[i], bfv[j],
                                                              acc[i][j], 0, 0, 0);
    }
    __syncthreads();
  }

  // epilogue: C/D layout col=lane&15, row=(lane>>4)*4+reg  [m89/m91 verified]
#pragma unroll
  for (int i = 0; i < 4; ++i) {
    const int mrow = m0 + mw + i * 16 + qd * 4;
#pragma unroll
    for (int j = 0; j < 4; ++j) {
      const int ncol = n0 + nw + j * 16 + li;
      const float bv = bias[ncol];
#pragma unroll
      for (int r = 0; r < 4; ++r) {
        const size_t off = (size_t)(mrow + r) * N + ncol;
        float v = acc[i][j][r] + bv;
        if (EPI == EPI_BIAS_RES_F32) {
          ((float*)out)[off] = v + (float)R[off];
        } else if (EPI == EPI_BIAS_GELU) {
          v = 0.5f * v * (1.f + erff(v * 0.70710678118654752f));
          ((bf16*)out)[off] = (bf16)v;
        } else {
          ((bf16*)out)[off] = (bf16)v;
        }
      }
    }
  }
}

// ---------------------------------------------------------------------------
// MFMA attention: one block (4 waves) per (sequence, head).
// P padded to PP (16-mult) for tiles; K-dim of PV padded to PK (32-mult).
// Phases: stage Q,K (swizzled bf16) + V^T | S=QK^T via mfma -> fp32 LDS |
// row softmax (unnormalized bf16 P, 1/sum saved) | O=PV via mfma, scaled.
// Pad cols of P and V^T are zeroed (no NaN); pad rows are discarded on store.
// ---------------------------------------------------------------------------
template <int P>
__global__ __launch_bounds__(256) void attn_kernel(const bf16* __restrict__ qkv,
                                                   bf16* __restrict__ out) {
  constexpr int PP   = ((P + 15) / 16) * 16;   // 32, 48, 96
  constexpr int PK   = ((PP + 31) / 32) * 32;  // 32, 64, 96
  constexpr int MT   = PP / 16;
  constexpr int SSTR = PP + 2;                 // fp32 words (2-way on C-write)
  constexpr int VSTR = PK + 8;                 // bf16 elems; *2B is 16B-mult
  constexpr int PSTR = PK + 8;

  __shared__ __align__(16) bf16 QK[2 * PP * 64];  // Q | K ; reused as Ps
  __shared__ __align__(16) bf16 Vt[64 * VSTR];
  __shared__ __align__(16) float Sm[PP * SSTR];
  __shared__ float rsum[PP];

  bf16* Qs = QK;
  bf16* Ks = QK + PP * 64;
  bf16* Ps = QK;  // overlays Q/K after S phase (dead by then)

  const int tid  = threadIdx.x;
  const int lane = tid & 63;
  const int wv   = tid >> 6;
  const int li   = lane & 15;
  const int qd   = lane >> 4;
  const int n    = blockIdx.x >> 3;
  const int h    = blockIdx.x & 7;
  const bf16* base = qkv + (size_t)n * P * QKV_D + h * 64;

  // stage Q,K: 16B chunks, slot = c ^ (r&7) (GEMM-verified conflict-free)
  for (int t = tid; t < P * 8; t += 256) {
    const int r = t >> 3, c = t & 7;
    const bf16x8 qv = *(const bf16x8*)(base + (size_t)r * QKV_D + c * 8);
    const bf16x8 kv = *(const bf16x8*)(base + (size_t)r * QKV_D + 512 + c * 8);
    *(bf16x8*)(Qs + r * 64 + ((c ^ (r & 7)) * 8)) = qv;
    *(bf16x8*)(Ks + r * 64 + ((c ^ (r & 7)) * 8)) = kv;
  }
  // stage V^T: Vt[d][j] = V[j][d]; j-major mapping -> LDS writes 2B apart
  for (int t = tid; t < P * 8; t += 256) {
    const int j = t % P, dc = t / P;
    const bf16x8 vv = *(const bf16x8*)(base + (size_t)j * QKV_D + 1024 + dc * 8);
#pragma unroll
    for (int u = 0; u < 8; ++u) Vt[(dc * 8 + u) * VSTR + j] = vv[u];
  }
  if constexpr (PK > P) {  // zero pad cols of V^T
    for (int t = tid; t < 64 * (PK - P); t += 256) {
      const int d = t / (PK - P), j = P + t % (PK - P);
      Vt[d * VSTR + j] = (bf16)0.f;
    }
  }
  __syncthreads();

  // S = Q K^T  (raw scores; 1/8 scale folded into softmax)
  for (int t = wv; t < MT * MT; t += 4) {
    const int ti = t / MT, tj = t % MT;
    f32x4 acc = (f32x4){0.f, 0.f, 0.f, 0.f};
#pragma unroll
    for (int ks = 0; ks < 2; ++ks) {
      const int ck = ks * 4 + qd;
      const int ar = ti * 16 + li;
      const int br = tj * 16 + li;
      const bf16x8 af = *(const bf16x8*)(Qs + ar * 64 + ((ck ^ (ar & 7)) * 8));
      const bf16x8 bv = *(const bf16x8*)(Ks + br * 64 + ((ck ^ (br & 7)) * 8));
      acc = __builtin_amdgcn_mfma_f32_16x16x32_bf16(af, bv, acc, 0, 0, 0);
    }
#pragma unroll
    for (int r = 0; r < 4; ++r)
      Sm[(ti * 16 + qd * 4 + r) * SSTR + tj * 16 + li] = acc[r];
  }
  __syncthreads();

  // softmax row i: unnormalized exp -> bf16 Ps; 1/sum saved for O-write
  if (tid < P) {
    const float* srow = Sm + tid * SSTR;
    bf16* prow = Ps + tid * PSTR;
    float mx = -1e30f;
    for (int j = 0; j < P; ++j) mx = fmaxf(mx, srow[j]);
    mx *= 0.125f;  // 1/sqrt(64)
    float sum = 0.f;
    for (int j = 0; j < P; ++j) {
      const float e = __expf(srow[j] * 0.125f - mx);
      sum += e;
      prow[j] = (bf16)e;
    }
    for (int j = P; j < PK; ++j) prow[j] = (bf16)0.f;
    rsum[tid] = 1.f / sum;
  }
  __syncthreads();

  // O = P V  (A = Ps rows, B = Vt rows; both plain stride, 2-way-free b128)
  for (int t = wv; t < MT * 4; t += 4) {
    const int ti = t >> 2, td = t & 3;
    f32x4 acc = (f32x4){0.f, 0.f, 0.f, 0.f};
#pragma unroll
    for (int ks = 0; ks < PK / 32; ++ks) {
      const int ck = ks * 4 + qd;
      const bf16x8 af = *(const bf16x8*)(Ps + (ti * 16 + li) * PSTR + ck * 8);
      const bf16x8 bv = *(const bf16x8*)(Vt + (td * 16 + li) * VSTR + ck * 8);
      acc = __builtin_amdgcn_mfma_f32_16x16x32_bf16(af, bv, acc, 0, 0, 0);
    }
#pragma unroll
    for (int r = 0; r < 4; ++r) {
      const int row = ti * 16 + qd * 4 + r;
      if (row < P)
        out[(size_t)(n * P + row) * HID + h * 64 + td * 16 + li] =
            (bf16)(acc[r] * rsum[row]);
    }
  }
}

// ---------------------------------------------------------------------------
// LayerNorm over 512, one wave per row. Y fp32 in, params fp32, bf16 out.
// ---------------------------------------------------------------------------
__global__ __launch_bounds__(256) void ln_kernel(const float* __restrict__ Y,
                                                 const float* __restrict__ w,
                                                 const float* __restrict__ b,
                                                 bf16* __restrict__ X) {
  const int row  = blockIdx.x * 4 + (threadIdx.x >> 6);
  const int lane = threadIdx.x & 63;
  const float* y = Y + (size_t)row * HID;
  float v[8], s = 0.f, s2 = 0.f;
#pragma unroll
  for (int j = 0; j < 8; ++j) {
    v[j] = y[lane + 64 * j];
    s += v[j];
    s2 += v[j] * v[j];
  }
#pragma unroll
  for (int off = 32; off > 0; off >>= 1) {
    s  += __shfl_xor(s, off, 64);
    s2 += __shfl_xor(s2, off, 64);
  }
  const float mean = s * (1.f / 512.f);
  const float var  = s2 * (1.f / 512.f) - mean * mean;
  const float rstd = rsqrtf(var + 1e-5f);
  bf16* xr = X + (size_t)row * HID;
#pragma unroll
  for (int j = 0; j < 8; ++j) {
    const int c = lane + 64 * j;
    xr[c] = (bf16)((v[j] - mean) * rstd * w[c] + b[c]);
  }
}

// ---------------------------------------------------------------------------
// input projection: h[r,o] = sum_k x[r,k]*w[o,k] + b[o], K=7. Writes the same
// value to nbr consecutive [TOKENS,HID] slices (branches share the input).
// ---------------------------------------------------------------------------
__global__ __launch_bounds__(256) void inproj_kernel(const float* __restrict__ x,
                                                     const float* __restrict__ w,
                                                     const float* __restrict__ b,
                                                     bf16* __restrict__ h,
                                                     int nbr) {
  const int idx = blockIdx.x * 256 + threadIdx.x;
  const int r = idx >> 9, o = idx & 511;
  float s = b[o];
#pragma unroll
  for (int k = 0; k < 7; ++k) s += x[r * 7 + k] * w[o * 7 + k];
  const bf16 bv = (bf16)s;
  for (int q = 0; q < nbr; ++q) h[idx + (size_t)q * TOKENS * HID] = bv;
}

// acc[row] (+)= X[row,:] . w  (per-branch final projection accumulate)
__global__ __launch_bounds__(256) void outdot_kernel(const bf16* __restrict__ X,
                                                     const float* __restrict__ w,
                                                     float* __restrict__ acc,
                                                     int first) {
  const int row  = blockIdx.x * 4 + (threadIdx.x >> 6);
  const int lane = threadIdx.x & 63;
  const bf16* xr = X + (size_t)row * HID;
  float s = 0.f;
#pragma unroll
  for (int j = 0; j < 8; ++j) {
    const int c = lane + 64 * j;
    s += (float)xr[c] * w[c];
  }
#pragma unroll
  for (int off = 32; off > 0; off >>= 1) s += __shfl_xor(s, off, 64);
  if (lane == 0) acc[row] = first ? s : (acc[row] + s);
}

// out[b,o] = (1/30) * sum_{j<10} acc[b*960 + o*10 + j] + b_out   (fp32 out)
__global__ __launch_bounds__(256) void pool_kernel(const float* __restrict__ acc,
                                                   const float* __restrict__ ob,
                                                   float* __restrict__ out) {
  const int idx = blockIdx.x * 256 + threadIdx.x;
  if (idx >= 16 * 96) return;
  const int bb = idx / 96, o = idx % 96;
  float s = 0.f;
#pragma unroll
  for (int j = 0; j < 10; ++j) s += acc[bb * 960 + o * 10 + j];
  out[idx] = s * (1.f / 30.f) + ob[0];
}

// ---------------------------------------------------------------------------
extern "C" void kernel_launch(void* const* d_in, const int* in_sizes, int n_in,
                              void* d_out, int out_size, void* d_ws,
                              size_t ws_size, hipStream_t stream) {
  const float* x          = (const float*)d_in[0];
  const float* ip_w       = (const float*)d_in[1];
  const float* ip_b       = (const float*)d_in[2];
  const float* in_proj_w  = (const float*)d_in[3];
  const float* in_proj_b  = (const float*)d_in[4];
  const float* out_proj_w = (const float*)d_in[5];
  const float* out_proj_b = (const float*)d_in[6];
  const float* ffn_w1     = (const float*)d_in[7];
  const float* ffn_b1     = (const float*)d_in[8];
  const float* ffn_w2     = (const float*)d_in[9];
  const float* ffn_b2     = (const float*)d_in[10];
  const float* ln1_w      = (const float*)d_in[11];
  const float* ln1_b      = (const float*)d_in[12];
  const float* ln2_w      = (const float*)d_in[13];
  const float* ln2_b      = (const float*)d_in[14];
  const float* op_w       = (const float*)d_in[15];
  const float* op_b       = (const float*)d_in[16];

  // fixed carve: weights + ACC, then activations (path-dependent)
  char* p = (char*)d_ws;
  bf16* Wq = (bf16*)p; p += (size_t)4 * QKV_D * HID * 2;
  bf16* Wo = (bf16*)p; p += (size_t)4 * HID * HID * 2;
  bf16* W1 = (bf16*)p; p += (size_t)4 * FFN_D * HID * 2;
  bf16* W2 = (bf16*)p; p += (size_t)4 * HID * FFN_D * 2;
  float* ACC = (float*)p; p += (size_t)TOKENS * 4;
  const size_t remain = ws_size - (size_t)(p - (char*)d_ws);

  const size_t T3 = 3 * (size_t)TOKENS;
  const size_t need_batched =
      T3 * HID * 4 + T3 * HID * 2 + T3 * FFN_D * 2;                // ~330 MB
  const size_t need_seq =
      (size_t)TOKENS * HID * 4 + (size_t)TOKENS * HID * 2 +
      (size_t)TOKENS * FFN_D * 2;                                  // ~110 MB
  const bool batched = remain >= need_batched;
  if (!batched && remain < need_seq) return;

  {  // weight conversion fp32 -> bf16
    const int nq = 4 * QKV_D * HID / 4, no = 4 * HID * HID / 4,
              n1 = 4 * FFN_D * HID / 4, n2 = 4 * HID * FFN_D / 4;
    cvt_kernel<<<(nq + 255) / 256, 256, 0, stream>>>(in_proj_w, Wq, nq);
    cvt_kernel<<<(no + 255) / 256, 256, 0, stream>>>(out_proj_w, Wo, no);
    cvt_kernel<<<(n1 + 255) / 256, 256, 0, stream>>>(ffn_w1, W1, n1);
    cvt_kernel<<<(n2 + 255) / 256, 256, 0, stream>>>(ffn_w2, W2, n2);
  }

  static const int periods[3] = {24, 48, 96};
  auto launch_attn = [&](int P, const bf16* q, bf16* o) {
    const int nblk = (TOKENS / P) * 8;
    if (P == 24)      attn_kernel<24><<<nblk, 256, 0, stream>>>(q, o);
    else if (P == 48) attn_kernel<48><<<nblk, 256, 0, stream>>>(q, o);
    else              attn_kernel<96><<<nblk, 256, 0, stream>>>(q, o);
  };

  if (batched) {
    // all 3 branches as one M = 3*TOKENS activation stream (shared weights)
    float* Y  = (float*)p; p += T3 * HID * 4;
    bf16* X   = (bf16*)p;  p += T3 * HID * 2;
    bf16* SCR = (bf16*)p;  p += T3 * FFN_D * 2;
    bf16* ATT = SCR + T3 * QKV_D;  // tail of SCR (qkv uses 1536 of 2048 cols)
    const int M = (int)T3, MB = M / 128;  // 360 m-tiles

    inproj_kernel<<<TOKENS * HID / 256, 256, 0, stream>>>(x, ip_w, ip_b, X, 3);
    for (int l = 0; l < 4; ++l) {
      gemm_bt<EPI_BIAS_BF16><<<dim3(MB, QKV_D / 128), 256, 0, stream>>>(
          X, Wq + (size_t)l * QKV_D * HID, in_proj_b + l * QKV_D, nullptr,
          SCR, M, QKV_D, HID);
      for (int br = 0; br < 3; ++br)
        launch_attn(periods[br], SCR + (size_t)br * TOKENS * QKV_D,
                    ATT + (size_t)br * TOKENS * HID);
      gemm_bt<EPI_BIAS_RES_F32><<<dim3(MB, HID / 128), 256, 0, stream>>>(
          ATT, Wo + (size_t)l * HID * HID, out_proj_b + l * HID, X, Y,
          M, HID, HID);
      ln_kernel<<<M / 4, 256, 0, stream>>>(Y, ln1_w + l * HID, ln1_b + l * HID, X);
      gemm_bt<EPI_BIAS_GELU><<<dim3(MB, FFN_D / 128), 256, 0, stream>>>(
          X, W1 + (size_t)l * FFN_D * HID, ffn_b1 + l * FFN_D, nullptr,
          SCR, M, FFN_D, HID);
      gemm_bt<EPI_BIAS_RES_F32><<<dim3(MB, HID / 128), 256, 0, stream>>>(
          SCR, W2 + (size_t)l * HID * FFN_D, ffn_b2 + l * HID, X, Y,
          M, HID, FFN_D);
      ln_kernel<<<M / 4, 256, 0, stream>>>(Y, ln2_w + l * HID, ln2_b + l * HID, X);
    }
    for (int br = 0; br < 3; ++br)
      outdot_kernel<<<TOKENS / 4, 256, 0, stream>>>(
          X + (size_t)br * TOKENS * HID, op_w, ACC, br == 0);
  } else {
    // sequential fallback (fits in ~135 MB)
    float* Y  = (float*)p; p += (size_t)TOKENS * HID * 4;
    bf16* X   = (bf16*)p;  p += (size_t)TOKENS * HID * 2;
    bf16* SCR = (bf16*)p;  p += (size_t)TOKENS * FFN_D * 2;
    bf16* ATT = SCR + (size_t)TOKENS * QKV_D;
    const int M = TOKENS, MB = M / 128;

    for (int br = 0; br < 3; ++br) {
      inproj_kernel<<<TOKENS * HID / 256, 256, 0, stream>>>(x, ip_w, ip_b, X, 1);
      for (int l = 0; l < 4; ++l) {
        gemm_bt<EPI_BIAS_BF16><<<dim3(MB, QKV_D / 128), 256, 0, stream>>>(
            X, Wq + (size_t)l * QKV_D * HID, in_proj_b + l * QKV_D, nullptr,
            SCR, M, QKV_D, HID);
        launch_attn(periods[br], SCR, ATT);
        gemm_bt<EPI_BIAS_RES_F32><<<dim3(MB, HID / 128), 256, 0, stream>>>(
            ATT, Wo + (size_t)l * HID * HID, out_proj_b + l * HID, X, Y,
            M, HID, HID);
        ln_kernel<<<M / 4, 256, 0, stream>>>(Y, ln1_w + l * HID,
                                             ln1_b + l * HID, X);
        gemm_bt<EPI_BIAS_GELU><<<dim3(MB, FFN_D / 128), 256, 0, stream>>>(
            X, W1 + (size_t)l * FFN_D * HID, ffn_b1 + l * FFN_D, nullptr,
            SCR, M, FFN_D, HID);
        gemm_bt<EPI_BIAS_RES_F32><<<dim3(MB, HID / 128), 256, 0, stream>>>(
            SCR, W2 + (size_t)l * HID * FFN_D, ffn_b2 + l * HID, X, Y,
            M, HID, FFN_D);
        ln_kernel<<<M / 4, 256, 0, stream>>>(Y, ln2_w + l * HID,
                                             ln2_b + l * HID, X);
      }
      outdot_kernel<<<TOKENS / 4, 256, 0, stream>>>(X, op_w, ACC, br == 0);
    }
  }
  pool_kernel<<<6, 256, 0, stream>>>(ACC, op_b, (float*)d_out);
}

// Round 4
// 2400.447 us; speedup vs baseline: 1.3057x; 1.0277x over previous
//
#include <hip/hip_runtime.h>
#include <hip/hip_bf16.h>

typedef __bf16 bf16;
typedef __attribute__((ext_vector_type(8))) __bf16 bf16x8;
typedef __attribute__((ext_vector_type(4))) __bf16 bf16x4;
typedef __attribute__((ext_vector_type(4))) float f32x4;

#define TOKENS 15360   // B*S = 16*960
#define HID    512
#define FFN_D  2048
#define QKV_D  1536

// ---------------------------------------------------------------------------
// fast exact-GELU: A&S 7.1.26 erf (|eps|<=1.5e-7), hw exp + hw rcp
// ---------------------------------------------------------------------------
__device__ __forceinline__ float gelu_erf(float x) {
  const float z = fabsf(x) * 0.70710678118654752f;
#if __has_builtin(__builtin_amdgcn_rcpf)
  const float t = __builtin_amdgcn_rcpf(fmaf(0.3275911f, z, 1.f));
#else
  const float t = 1.f / fmaf(0.3275911f, z, 1.f);
#endif
  float p = fmaf(1.061405429f, t, -1.453152027f);
  p = fmaf(p, t, 1.421413741f);
  p = fmaf(p, t, -0.284496736f);
  p = fmaf(p, t, 0.254829592f);
  p *= t;
  const float e  = __expf(-z * z);
  const float er = fmaf(-p, e, 1.f);          // erf(|x|/sqrt2)
  return 0.5f * x * (1.f + copysignf(er, x));
}

// ---------------------------------------------------------------------------
// fp32 -> bf16 weight conversion (run every launch; ws is re-poisoned)
// ---------------------------------------------------------------------------
__global__ __launch_bounds__(256) void cvt_kernel(const float* __restrict__ src,
                                                  bf16* __restrict__ dst, int n4) {
  const int i = (blockIdx.x * 256 + threadIdx.x);
  if (i >= n4) return;
  const float4 v = ((const float4*)src)[i];
  bf16x4 d = {(bf16)v.x, (bf16)v.y, (bf16)v.z, (bf16)v.w};
  *(bf16x4*)(dst + (size_t)i * 4) = d;
}

// ---------------------------------------------------------------------------
// GEMM: C[M,N] = A[M,K] @ W[N,K]^T (+bias fp32, + optional residual / GELU)
// 128x128 tile, BK=64, 4 waves, each 64x64 via 4x4 mfma_f32_16x16x32_bf16.
// LDS staged with global_load_lds width=16; XOR swizzle (slot c holds k-chunk
// c^(r&7)) keeps async-copy contiguity AND makes ds_read_b128 2-way (free).
// ---------------------------------------------------------------------------
#define EPI_BIAS_BF16     0
#define EPI_BIAS_RES_F32  1
#define EPI_BIAS_GELU     2

template <int EPI>
__global__ __launch_bounds__(256) void gemm_bt(
    const bf16* __restrict__ A, const bf16* __restrict__ W,
    const float* __restrict__ bias, const bf16* __restrict__ R,
    void* __restrict__ out, int M, int N, int K) {
  __shared__ __align__(16) bf16 As[128 * 64];
  __shared__ __align__(16) bf16 Bs[128 * 64];

  const int tid  = threadIdx.x;
  const int lane = tid & 63;
  const int wv   = tid >> 6;
  const int li   = lane & 15;
  const int qd   = lane >> 4;
  const int mw   = (wv & 1) << 6;
  const int nw   = (wv >> 1) << 6;
  const int m0   = blockIdx.x << 7;
  const int n0   = blockIdx.y << 7;

  f32x4 acc[4][4];
#pragma unroll
  for (int i = 0; i < 4; ++i)
#pragma unroll
    for (int j = 0; j < 4; ++j) acc[i][j] = (f32x4){0.f, 0.f, 0.f, 0.f};

  // staging addresses: tid-invariant parts hoisted; pointers advance by BK
  const bf16* pa[4];
  const bf16* pb[4];
  bf16* da[4];
  bf16* db[4];
#pragma unroll
  for (int it = 0; it < 4; ++it) {
    const int fc   = it * 256 + tid;
    const int r    = fc >> 3;
    const int c    = fc & 7;
    const int koff = (c ^ (r & 7)) << 3;
    pa[it] = A + (size_t)(m0 + r) * K + koff;
    pb[it] = W + (size_t)(n0 + r) * K + koff;
    da[it] = As + (size_t)(it * 256 + (tid & 192)) * 8;  // wave-uniform base
    db[it] = Bs + (size_t)(it * 256 + (tid & 192)) * 8;
  }

  for (int k0 = 0; k0 < K; k0 += 64) {
#pragma unroll
    for (int it = 0; it < 4; ++it) {
      __builtin_amdgcn_global_load_lds(
          (const __attribute__((address_space(1))) unsigned int*)pa[it],
          (__attribute__((address_space(3))) unsigned int*)da[it], 16, 0, 0);
      __builtin_amdgcn_global_load_lds(
          (const __attribute__((address_space(1))) unsigned int*)pb[it],
          (__attribute__((address_space(3))) unsigned int*)db[it], 16, 0, 0);
      pa[it] += 64;
      pb[it] += 64;
    }
    __syncthreads();

#pragma unroll
    for (int ks = 0; ks < 2; ++ks) {
      const int ck = (ks << 2) + qd;         // A/B frag: k-chunk = quad (+4*ks)
      bf16x8 af[4], bfv[4];
#pragma unroll
      for (int i = 0; i < 4; ++i) {
        const int mr = mw + i * 16 + li;     // mr&7 == li&7
        af[i] = *(const bf16x8*)(As + mr * 64 + ((ck ^ (li & 7)) << 3));
      }
#pragma unroll
      for (int j = 0; j < 4; ++j) {
        const int nr = nw + j * 16 + li;
        bfv[j] = *(const bf16x8*)(Bs + nr * 64 + ((ck ^ (li & 7)) << 3));
      }
#pragma unroll
      for (int i = 0; i < 4; ++i)
#pragma unroll
        for (int j = 0; j < 4; ++j)
          acc[i][j] = __builtin_amdgcn_mfma_f32_16x16x32_bf16(af[i], bfv[j],
                                                              acc[i][j], 0, 0, 0);
    }
    __syncthreads();
  }

  // epilogue: C/D layout col=lane&15, row=(lane>>4)*4+reg  [m89/m91 verified]
#pragma unroll
  for (int i = 0; i < 4; ++i) {
    const int mrow = m0 + mw + i * 16 + qd * 4;
#pragma unroll
    for (int j = 0; j < 4; ++j) {
      const int ncol = n0 + nw + j * 16 + li;
      const float bv = bias[ncol];
#pragma unroll
      for (int r = 0; r < 4; ++r) {
        const size_t off = (size_t)(mrow + r) * N + ncol;
        float v = acc[i][j][r] + bv;
        if (EPI == EPI_BIAS_RES_F32) {
          ((float*)out)[off] = v + (float)R[off];
        } else if (EPI == EPI_BIAS_GELU) {
          ((bf16*)out)[off] = (bf16)gelu_erf(v);
        } else {
          ((bf16*)out)[off] = (bf16)v;
        }
      }
    }
  }
}

// ---------------------------------------------------------------------------
// MFMA attention: one block (4 waves) per (sequence, head).
// P padded to PP (16-mult) for tiles; K-dim of PV padded to PK (32-mult).
// ---------------------------------------------------------------------------
template <int P>
__global__ __launch_bounds__(256) void attn_kernel(const bf16* __restrict__ qkv,
                                                   bf16* __restrict__ out) {
  constexpr int PP   = ((P + 15) / 16) * 16;   // 32, 48, 96
  constexpr int PK   = ((PP + 31) / 32) * 32;  // 32, 64, 96
  constexpr int MT   = PP / 16;
  constexpr int SSTR = PP + 2;                 // fp32 words
  constexpr int VSTR = PK + 8;                 // bf16 elems; *2B is 16B-mult
  constexpr int PSTR = PK + 8;

  __shared__ __align__(16) bf16 QK[2 * PP * 64];  // Q | K ; reused as Ps
  __shared__ __align__(16) bf16 Vt[64 * VSTR];
  __shared__ __align__(16) float Sm[PP * SSTR];
  __shared__ float rsum[PP];

  bf16* Qs = QK;
  bf16* Ks = QK + PP * 64;
  bf16* Ps = QK;  // overlays Q/K after S phase (dead by then)

  const int tid  = threadIdx.x;
  const int lane = tid & 63;
  const int wv   = tid >> 6;
  const int li   = lane & 15;
  const int qd   = lane >> 4;
  const int n    = blockIdx.x >> 3;
  const int h    = blockIdx.x & 7;
  const bf16* base = qkv + (size_t)n * P * QKV_D + h * 64;

  // stage Q,K: 16B chunks, slot = c ^ (r&7)
  for (int t = tid; t < P * 8; t += 256) {
    const int r = t >> 3, c = t & 7;
    const bf16x8 qv = *(const bf16x8*)(base + (size_t)r * QKV_D + c * 8);
    const bf16x8 kv = *(const bf16x8*)(base + (size_t)r * QKV_D + 512 + c * 8);
    *(bf16x8*)(Qs + r * 64 + ((c ^ (r & 7)) * 8)) = qv;
    *(bf16x8*)(Ks + r * 64 + ((c ^ (r & 7)) * 8)) = kv;
  }
  // stage V^T
  for (int t = tid; t < P * 8; t += 256) {
    const int j = t % P, dc = t / P;
    const bf16x8 vv = *(const bf16x8*)(base + (size_t)j * QKV_D + 1024 + dc * 8);
#pragma unroll
    for (int u = 0; u < 8; ++u) Vt[(dc * 8 + u) * VSTR + j] = vv[u];
  }
  if constexpr (PK > P) {
    for (int t = tid; t < 64 * (PK - P); t += 256) {
      const int d = t / (PK - P), j = P + t % (PK - P);
      Vt[d * VSTR + j] = (bf16)0.f;
    }
  }
  __syncthreads();

  // S = Q K^T
  for (int t = wv; t < MT * MT; t += 4) {
    const int ti = t / MT, tj = t % MT;
    f32x4 acc = (f32x4){0.f, 0.f, 0.f, 0.f};
#pragma unroll
    for (int ks = 0; ks < 2; ++ks) {
      const int ck = ks * 4 + qd;
      const int ar = ti * 16 + li;
      const int br = tj * 16 + li;
      const bf16x8 af = *(const bf16x8*)(Qs + ar * 64 + ((ck ^ (ar & 7)) * 8));
      const bf16x8 bv = *(const bf16x8*)(Ks + br * 64 + ((ck ^ (br & 7)) * 8));
      acc = __builtin_amdgcn_mfma_f32_16x16x32_bf16(af, bv, acc, 0, 0, 0);
    }
#pragma unroll
    for (int r = 0; r < 4; ++r)
      Sm[(ti * 16 + qd * 4 + r) * SSTR + tj * 16 + li] = acc[r];
  }
  __syncthreads();

  // softmax row: unnormalized exp -> bf16 Ps; 1/sum saved for O-write
  if (tid < P) {
    const float* srow = Sm + tid * SSTR;
    bf16* prow = Ps + tid * PSTR;
    float mx = -1e30f;
    for (int j = 0; j < P; ++j) mx = fmaxf(mx, srow[j]);
    mx *= 0.125f;  // 1/sqrt(64)
    float sum = 0.f;
    for (int j = 0; j < P; ++j) {
      const float e = __expf(srow[j] * 0.125f - mx);
      sum += e;
      prow[j] = (bf16)e;
    }
    for (int j = P; j < PK; ++j) prow[j] = (bf16)0.f;
    rsum[tid] = 1.f / sum;
  }
  __syncthreads();

  // O = P V
  for (int t = wv; t < MT * 4; t += 4) {
    const int ti = t >> 2, td = t & 3;
    f32x4 acc = (f32x4){0.f, 0.f, 0.f, 0.f};
#pragma unroll
    for (int ks = 0; ks < PK / 32; ++ks) {
      const int ck = ks * 4 + qd;
      const bf16x8 af = *(const bf16x8*)(Ps + (ti * 16 + li) * PSTR + ck * 8);
      const bf16x8 bv = *(const bf16x8*)(Vt + (td * 16 + li) * VSTR + ck * 8);
      acc = __builtin_amdgcn_mfma_f32_16x16x32_bf16(af, bv, acc, 0, 0, 0);
    }
#pragma unroll
    for (int r = 0; r < 4; ++r) {
      const int row = ti * 16 + qd * 4 + r;
      if (row < P)
        out[(size_t)(n * P + row) * HID + h * 64 + td * 16 + li] =
            (bf16)(acc[r] * rsum[row]);
    }
  }
}

// ---------------------------------------------------------------------------
// LayerNorm over 512, one wave per row. float4 loads, bf16x4 stores.
// ---------------------------------------------------------------------------
__global__ __launch_bounds__(256) void ln_kernel(const float* __restrict__ Y,
                                                 const float* __restrict__ w,
                                                 const float* __restrict__ b,
                                                 bf16* __restrict__ X) {
  const int row  = blockIdx.x * 4 + (threadIdx.x >> 6);
  const int lane = threadIdx.x & 63;
  const float4* y4 = (const float4*)(Y + (size_t)row * HID);
  const float4 u = y4[lane];
  const float4 v = y4[lane + 64];
  float s  = u.x + u.y + u.z + u.w + v.x + v.y + v.z + v.w;
  float s2 = u.x*u.x + u.y*u.y + u.z*u.z + u.w*u.w +
             v.x*v.x + v.y*v.y + v.z*v.z + v.w*v.w;
#pragma unroll
  for (int off = 32; off > 0; off >>= 1) {
    s  += __shfl_xor(s, off, 64);
    s2 += __shfl_xor(s2, off, 64);
  }
  const float mean = s * (1.f / 512.f);
  const float var  = s2 * (1.f / 512.f) - mean * mean;
  const float rstd = rsqrtf(var + 1e-5f);
  const float4 w0 = ((const float4*)w)[lane];
  const float4 w1 = ((const float4*)w)[lane + 64];
  const float4 b0 = ((const float4*)b)[lane];
  const float4 b1 = ((const float4*)b)[lane + 64];
  bf16* xr = X + (size_t)row * HID;
  bf16x4 o0 = {(bf16)((u.x - mean) * rstd * w0.x + b0.x),
               (bf16)((u.y - mean) * rstd * w0.y + b0.y),
               (bf16)((u.z - mean) * rstd * w0.z + b0.z),
               (bf16)((u.w - mean) * rstd * w0.w + b0.w)};
  bf16x4 o1 = {(bf16)((v.x - mean) * rstd * w1.x + b1.x),
               (bf16)((v.y - mean) * rstd * w1.y + b1.y),
               (bf16)((v.z - mean) * rstd * w1.z + b1.z),
               (bf16)((v.w - mean) * rstd * w1.w + b1.w)};
  *(bf16x4*)(xr + 4 * lane)       = o0;
  *(bf16x4*)(xr + 256 + 4 * lane) = o1;
}

// ---------------------------------------------------------------------------
// input projection: h[r,o] = sum_k x[r,k]*w[o,k] + b[o], K=7. Writes the same
// value to nbr consecutive [TOKENS,HID] slices (branches share the input).
// ---------------------------------------------------------------------------
__global__ __launch_bounds__(256) void inproj_kernel(const float* __restrict__ x,
                                                     const float* __restrict__ w,
                                                     const float* __restrict__ b,
                                                     bf16* __restrict__ h,
                                                     int nbr) {
  const int idx = blockIdx.x * 256 + threadIdx.x;
  const int r = idx >> 9, o = idx & 511;
  float s = b[o];
#pragma unroll
  for (int k = 0; k < 7; ++k) s += x[r * 7 + k] * w[o * 7 + k];
  const bf16 bv = (bf16)s;
  for (int q = 0; q < nbr; ++q) h[idx + (size_t)q * TOKENS * HID] = bv;
}

// acc[row] (+)= X[row,:] . w  (per-branch final projection accumulate)
__global__ __launch_bounds__(256) void outdot_kernel(const bf16* __restrict__ X,
                                                     const float* __restrict__ w,
                                                     float* __restrict__ acc,
                                                     int first) {
  const int row  = blockIdx.x * 4 + (threadIdx.x >> 6);
  const int lane = threadIdx.x & 63;
  const bf16* xr = X + (size_t)row * HID;
  const bf16x8 xa = *(const bf16x8*)(xr + 8 * lane);
  const float4 wa = ((const float4*)w)[2 * lane];
  const float4 wb = ((const float4*)w)[2 * lane + 1];
  float s = (float)xa[0] * wa.x + (float)xa[1] * wa.y + (float)xa[2] * wa.z +
            (float)xa[3] * wa.w + (float)xa[4] * wb.x + (float)xa[5] * wb.y +
            (float)xa[6] * wb.z + (float)xa[7] * wb.w;
#pragma unroll
  for (int off = 32; off > 0; off >>= 1) s += __shfl_xor(s, off, 64);
  if (lane == 0) acc[row] = first ? s : (acc[row] + s);
}

// out[b,o] = (1/30) * sum_{j<10} acc[b*960 + o*10 + j] + b_out   (fp32 out)
__global__ __launch_bounds__(256) void pool_kernel(const float* __restrict__ acc,
                                                   const float* __restrict__ ob,
                                                   float* __restrict__ out) {
  const int idx = blockIdx.x * 256 + threadIdx.x;
  if (idx >= 16 * 96) return;
  const int bb = idx / 96, o = idx % 96;
  float s = 0.f;
#pragma unroll
  for (int j = 0; j < 10; ++j) s += acc[bb * 960 + o * 10 + j];
  out[idx] = s * (1.f / 30.f) + ob[0];
}

// ---------------------------------------------------------------------------
extern "C" void kernel_launch(void* const* d_in, const int* in_sizes, int n_in,
                              void* d_out, int out_size, void* d_ws,
                              size_t ws_size, hipStream_t stream) {
  const float* x          = (const float*)d_in[0];
  const float* ip_w       = (const float*)d_in[1];
  const float* ip_b       = (const float*)d_in[2];
  const float* in_proj_w  = (const float*)d_in[3];
  const float* in_proj_b  = (const float*)d_in[4];
  const float* out_proj_w = (const float*)d_in[5];
  const float* out_proj_b = (const float*)d_in[6];
  const float* ffn_w1     = (const float*)d_in[7];
  const float* ffn_b1     = (const float*)d_in[8];
  const float* ffn_w2     = (const float*)d_in[9];
  const float* ffn_b2     = (const float*)d_in[10];
  const float* ln1_w      = (const float*)d_in[11];
  const float* ln1_b      = (const float*)d_in[12];
  const float* ln2_w      = (const float*)d_in[13];
  const float* ln2_b      = (const float*)d_in[14];
  const float* op_w       = (const float*)d_in[15];
  const float* op_b       = (const float*)d_in[16];

  // fixed carve: weights + ACC, then activations (path-dependent)
  char* p = (char*)d_ws;
  bf16* Wq = (bf16*)p; p += (size_t)4 * QKV_D * HID * 2;
  bf16* Wo = (bf16*)p; p += (size_t)4 * HID * HID * 2;
  bf16* W1 = (bf16*)p; p += (size_t)4 * FFN_D * HID * 2;
  bf16* W2 = (bf16*)p; p += (size_t)4 * HID * FFN_D * 2;
  float* ACC = (float*)p; p += (size_t)TOKENS * 4;
  const size_t remain = ws_size - (size_t)(p - (char*)d_ws);

  const size_t T3 = 3 * (size_t)TOKENS;
  const size_t need_batched =
      T3 * HID * 4 + T3 * HID * 2 + T3 * FFN_D * 2;                // ~330 MB
  const size_t need_seq =
      (size_t)TOKENS * HID * 4 + (size_t)TOKENS * HID * 2 +
      (size_t)TOKENS * FFN_D * 2;                                  // ~110 MB
  const bool batched = remain >= need_batched;
  if (!batched && remain < need_seq) return;

  {  // weight conversion fp32 -> bf16
    const int nq = 4 * QKV_D * HID / 4, no = 4 * HID * HID / 4,
              n1 = 4 * FFN_D * HID / 4, n2 = 4 * HID * FFN_D / 4;
    cvt_kernel<<<(nq + 255) / 256, 256, 0, stream>>>(in_proj_w, Wq, nq);
    cvt_kernel<<<(no + 255) / 256, 256, 0, stream>>>(out_proj_w, Wo, no);
    cvt_kernel<<<(n1 + 255) / 256, 256, 0, stream>>>(ffn_w1, W1, n1);
    cvt_kernel<<<(n2 + 255) / 256, 256, 0, stream>>>(ffn_w2, W2, n2);
  }

  static const int periods[3] = {24, 48, 96};
  auto launch_attn = [&](int P, const bf16* q, bf16* o) {
    const int nblk = (TOKENS / P) * 8;
    if (P == 24)      attn_kernel<24><<<nblk, 256, 0, stream>>>(q, o);
    else if (P == 48) attn_kernel<48><<<nblk, 256, 0, stream>>>(q, o);
    else              attn_kernel<96><<<nblk, 256, 0, stream>>>(q, o);
  };

  if (batched) {
    float* Y  = (float*)p; p += T3 * HID * 4;
    bf16* X   = (bf16*)p;  p += T3 * HID * 2;
    bf16* SCR = (bf16*)p;  p += T3 * FFN_D * 2;
    bf16* ATT = SCR + T3 * QKV_D;  // tail of SCR
    const int M = (int)T3, MB = M / 128;

    inproj_kernel<<<TOKENS * HID / 256, 256, 0, stream>>>(x, ip_w, ip_b, X, 3);
    for (int l = 0; l < 4; ++l) {
      gemm_bt<EPI_BIAS_BF16><<<dim3(MB, QKV_D / 128), 256, 0, stream>>>(
          X, Wq + (size_t)l * QKV_D * HID, in_proj_b + l * QKV_D, nullptr,
          SCR, M, QKV_D, HID);
      for (int br = 0; br < 3; ++br)
        launch_attn(periods[br], SCR + (size_t)br * TOKENS * QKV_D,
                    ATT + (size_t)br * TOKENS * HID);
      gemm_bt<EPI_BIAS_RES_F32><<<dim3(MB, HID / 128), 256, 0, stream>>>(
          ATT, Wo + (size_t)l * HID * HID, out_proj_b + l * HID, X, Y,
          M, HID, HID);
      ln_kernel<<<M / 4, 256, 0, stream>>>(Y, ln1_w + l * HID, ln1_b + l * HID, X);
      gemm_bt<EPI_BIAS_GELU><<<dim3(MB, FFN_D / 128), 256, 0, stream>>>(
          X, W1 + (size_t)l * FFN_D * HID, ffn_b1 + l * FFN_D, nullptr,
          SCR, M, FFN_D, HID);
      gemm_bt<EPI_BIAS_RES_F32><<<dim3(MB, HID / 128), 256, 0, stream>>>(
          SCR, W2 + (size_t)l * HID * FFN_D, ffn_b2 + l * HID, X, Y,
          M, HID, FFN_D);
      ln_kernel<<<M / 4, 256, 0, stream>>>(Y, ln2_w + l * HID, ln2_b + l * HID, X);
    }
    for (int br = 0; br < 3; ++br)
      outdot_kernel<<<TOKENS / 4, 256, 0, stream>>>(
          X + (size_t)br * TOKENS * HID, op_w, ACC, br == 0);
  } else {
    // sequential (fits in ~135 MB)
    float* Y  = (float*)p; p += (size_t)TOKENS * HID * 4;
    bf16* X   = (bf16*)p;  p += (size_t)TOKENS * HID * 2;
    bf16* SCR = (bf16*)p;  p += (size_t)TOKENS * FFN_D * 2;
    bf16* ATT = SCR + (size_t)TOKENS * QKV_D;
    const int M = TOKENS, MB = M / 128;

    for (int br = 0; br < 3; ++br) {
      inproj_kernel<<<TOKENS * HID / 256, 256, 0, stream>>>(x, ip_w, ip_b, X, 1);
      for (int l = 0; l < 4; ++l) {
        gemm_bt<EPI_BIAS_BF16><<<dim3(MB, QKV_D / 128), 256, 0, stream>>>(
            X, Wq + (size_t)l * QKV_D * HID, in_proj_b + l * QKV_D, nullptr,
            SCR, M, QKV_D, HID);
        launch_attn(periods[br], SCR, ATT);
        gemm_bt<EPI_BIAS_RES_F32><<<dim3(MB, HID / 128), 256, 0, stream>>>(
            ATT, Wo + (size_t)l * HID * HID, out_proj_b + l * HID, X, Y,
            M, HID, HID);
        ln_kernel<<<M / 4, 256, 0, stream>>>(Y, ln1_w + l * HID,
                                             ln1_b + l * HID, X);
        gemm_bt<EPI_BIAS_GELU><<<dim3(MB, FFN_D / 128), 256, 0, stream>>>(
            X, W1 + (size_t)l * FFN_D * HID, ffn_b1 + l * FFN_D, nullptr,
            SCR, M, FFN_D, HID);
        gemm_bt<EPI_BIAS_RES_F32><<<dim3(MB, HID / 128), 256, 0, stream>>>(
            SCR, W2 + (size_t)l * HID * FFN_D, ffn_b2 + l * HID, X, Y,
            M, HID, FFN_D);
        ln_kernel<<<M / 4, 256, 0, stream>>>(Y, ln2_w + l * HID,
                                             ln2_b + l * HID, X);
      }
      outdot_kernel<<<TOKENS / 4, 256, 0, stream>>>(X, op_w, ACC, br == 0);
    }
  }
  pool_kernel<<<6, 256, 0, stream>>>(ACC, op_b, (float*)d_out);
}